// Round 6
// baseline (8282.297 us; speedup 1.0000x reference)
//
#include <hip/hip_runtime.h>

// TimeLSTM persistent-scan, round 6: round-3 structure (grid 128, 4 groups x
// 32 members, 16 batches/group, agent-scope atomics ONLY — no sc0, no XCD
// detection) with a minimal-RT exchange: per-dword in-band tags.
// Each exchanged value is a dword (tag16<<16)|f16payload, stored/loaded with
// relaxed agent atomics (proven coherent at MALL in rounds 2/3). A dword
// store is natively atomic -> no tearing; readiness + data in one RT; no
// flag store, no drain, no separate poll. Phases double-buffered by t&1
// (induction: a producer reaches phase-p overwrite with tag T+2 only after
// every WG gathered tag T from phase p). 0xAA poison = tag 0xAAAA > 1023,
// so unwritten cells never match and no workspace memset is needed.

typedef _Float16 f16;
typedef _Float16 f16x8 __attribute__((ext_vector_type(8)));
typedef float f32x4 __attribute__((ext_vector_type(4)));

#define S_ 1024
#define IN_ 256
#define H_ 512
#define ECONST 2.718281828459045f

__device__ __forceinline__ float sigf(float x) { return 1.0f / (1.0f + __expf(-x)); }
__device__ __forceinline__ float tanh_f(float x) { return 1.0f - 2.0f / (__expf(2.0f * x) + 1.0f); }

__device__ __forceinline__ unsigned short f16bits(float x) {
    union { f16 f; unsigned short u; } p; p.f = (f16)x; return p.u;
}

__launch_bounds__(320, 1)
__global__ void tlstm_scan(
    const float* __restrict__ inputs, const float* __restrict__ tstamps,
    const int* __restrict__ lens,
    const float* __restrict__ W_all, const float* __restrict__ b_all,
    const float* __restrict__ U_all, const float* __restrict__ b_u,
    const float* __restrict__ W_d, const float* __restrict__ b_d,
    float* __restrict__ out0, float* __restrict__ out1, float* __restrict__ out2,
    unsigned int* __restrict__ hbuf, unsigned int* __restrict__ cbuf)
{
    __shared__ __align__(16) f16 A_sm[96 * 16 * 8];   // 24 KB (h kb0..63, x kb64..95)
    __shared__ __align__(16) f16 C_sm[64 * 16 * 8];   // 16 KB (c operand)
    __shared__ float outs_sm[5 * 16 * 17];            // +1 pad on col
    __shared__ float c_loc[16 * 16];                  // fp32 c state (own cells)
    __shared__ float bias_sm[5 * 16];
    __shared__ int   len_sm[16];

    const int tid    = threadIdx.x;
    const int grp    = blockIdx.x & 3;     // 4 groups x 16 batches
    const int member = blockIdx.x >> 2;    // 32 members, 16 cols each
    const int wave   = tid >> 6;
    const int lane   = tid & 63;
    const int q      = lane >> 4;
    const int r16    = lane & 15;
    const int j0     = member * 16;

    // ---------- weights -> VGPR B-fragments (reused all 1024 steps) ----------
    // B[k][n]: n = lane&15, k = kk*32 + q*8 + e
    f16x8 bw[24];
    if (wave < 4) {
        const int col = wave * 512 + j0 + r16;
#pragma unroll
        for (int kk = 0; kk < 24; ++kk) {
            f16x8 v;
            const int kbase = kk * 32 + q * 8;
#pragma unroll
            for (int e = 0; e < 8; ++e) {
                const int k = kbase + e;
                const float w = (kk < 16) ? W_all[k * 2048 + col]
                                          : U_all[(k - 512) * 2048 + col];
                v[e] = (f16)w;
            }
            bw[kk] = v;
        }
    } else {
        const int col = j0 + r16;
#pragma unroll
        for (int kk = 0; kk < 16; ++kk) {
            f16x8 v;
            const int kbase = kk * 32 + q * 8;
#pragma unroll
            for (int e = 0; e < 8; ++e) v[e] = (f16)W_d[(kbase + e) * 512 + col];
            bw[kk] = v;
        }
#pragma unroll
        for (int kk = 16; kk < 24; ++kk) bw[kk] = bw[0];
    }

    // ---------- LDS init ----------
    {
        uint4 z; z.x = z.y = z.z = z.w = 0u;
        uint4* a4 = (uint4*)A_sm;
        uint4* c4 = (uint4*)C_sm;
        for (int i = tid; i < 1024; i += 320) { a4[i] = z; c4[i] = z; }
        if (tid < 256) c_loc[tid] = 0.0f;
        if (tid < 64) {
            const int w = tid >> 4, n = tid & 15;
            const int col = w * 512 + j0 + n;
            bias_sm[w * 16 + n] = b_all[col] + b_u[col];
        } else if (tid < 80) {
            bias_sm[64 + (tid & 15)] = b_d[j0 + (tid & 15)];
        }
        if (tid < 16) len_sm[tid] = lens[grp * 16 + tid];
        // stage x(0) into A_sm kb 64..95 (16 batches x 64 float4)
        for (int idx = tid; idx < 1024; idx += 320) {
            const int b = idx >> 6;
            const int kx0 = (idx & 63) << 2;
            const float4 v = *(const float4*)&inputs[(((size_t)(grp * 16 + b)) * S_) * IN_ + kx0];
            union { f16 h[4]; uint2 u; } p;
            p.h[0] = (f16)v.x; p.h[1] = (f16)v.y; p.h[2] = (f16)v.z; p.h[3] = (f16)v.w;
            *(uint2*)&A_sm[((64 + (kx0 >> 3)) * 16 + b) * 8 + (kx0 & 7)] = p.u;
        }
    }
    __syncthreads();

    // per-group exchange: h and c arrays, 2 phases x 8192 dwords each
    unsigned int* const hb_g = hbuf + (size_t)grp * 16384;
    unsigned int* const cb_g = cbuf + (size_t)grp * 16384;

    for (int t = 0; t < S_; ++t) {
        float ts = 0.0f;
        if (tid < 256) ts = tstamps[(size_t)(grp * 16 + (tid >> 4)) * S_ + t];

        // ---------- MFMA ----------
        f32x4 acc0 = {0.f, 0.f, 0.f, 0.f}, acc1 = {0.f, 0.f, 0.f, 0.f};
        if (wave < 4) {
            const f16* abase = &A_sm[(q * 16 + r16) * 8];
#pragma unroll
            for (int kk = 0; kk < 24; ++kk) {
                const f16x8 a = *(const f16x8*)(abase + kk * 512);
                if (kk & 1) acc1 = __builtin_amdgcn_mfma_f32_16x16x32_f16(a, bw[kk], acc1, 0, 0, 0);
                else        acc0 = __builtin_amdgcn_mfma_f32_16x16x32_f16(a, bw[kk], acc0, 0, 0, 0);
            }
        } else {
            const f16* abase = &C_sm[(q * 16 + r16) * 8];
#pragma unroll
            for (int kk = 0; kk < 16; ++kk) {
                const f16x8 a = *(const f16x8*)(abase + kk * 512);
                if (kk & 1) acc1 = __builtin_amdgcn_mfma_f32_16x16x32_f16(a, bw[kk], acc1, 0, 0, 0);
                else        acc0 = __builtin_amdgcn_mfma_f32_16x16x32_f16(a, bw[kk], acc0, 0, 0, 0);
            }
        }
        const f32x4 acc = acc0 + acc1;
        // C/D: col = lane&15, row = quad*4 + reg (row = batch)
#pragma unroll
        for (int r = 0; r < 4; ++r)
            outs_sm[(wave * 16 + q * 4 + r) * 17 + r16] = acc[r];
        __syncthreads();

        const unsigned int tag = (unsigned int)(t + 1);     // 1..1024, < 0xAAAA
        unsigned int* const hph = hb_g + (t & 1) * 8192;
        unsigned int* const cph = cb_g + (t & 1) * 8192;

        // ---------- gates + tagged publish ----------
        if (tid < 256) {
            const int b = tid >> 4, jj = tid & 15;
            const int gb = grp * 16 + b;
            const float f  = outs_sm[(0 * 16 + b) * 17 + jj] + bias_sm[0  + jj];
            const float i_ = outs_sm[(1 * 16 + b) * 17 + jj] + bias_sm[16 + jj];
            const float o  = outs_sm[(2 * 16 + b) * 17 + jj] + bias_sm[32 + jj];
            const float ct = outs_sm[(3 * 16 + b) * 17 + jj] + bias_sm[48 + jj];
            const float d  = outs_sm[(4 * 16 + b) * 17 + jj] + bias_sm[64 + jj];
            const float gt = 1.0f / __logf(ECONST + ts);
            const float cs1   = tanh_f(d);
            const float cprev = c_loc[tid];
            const float cadj  = cprev - cs1 + cs1 * gt;
            const float cnew  = sigf(f) * cadj + sigf(i_) * tanh_f(ct);
            const float hnew  = sigf(o) * tanh_f(cnew);
            c_loc[tid] = cnew;
            const int col = j0 + jj;
            const int len = len_sm[b];
            out0[((size_t)gb * S_ + t) * H_ + col] = (t < len) ? hnew : 0.0f;
            if (t == len - 1) {
                out1[gb * H_ + col] = hnew;
                out2[gb * H_ + col] = cnew;
            }
            if (t < S_ - 1) {
                // cell index within slice = b*16 + jj = tid; slice base = member*256
                const int ci = member * 256 + tid;
                __hip_atomic_store(hph + ci, (tag << 16) | (unsigned int)f16bits(hnew),
                                   __ATOMIC_RELAXED, __HIP_MEMORY_SCOPE_AGENT);
                __hip_atomic_store(cph + ci, (tag << 16) | (unsigned int)f16bits(cnew),
                                   __ATOMIC_RELAXED, __HIP_MEMORY_SCOPE_AGENT);
            }
        }

        if (t < S_ - 1) {
            // x(t+1) loads issued now; latency hides under the gather poll
            float4 xv[4];
            if (tid < 256) {
#pragma unroll
                for (int k2 = 0; k2 < 4; ++k2) {
                    const int idx = k2 * 256 + tid;
                    const int b = idx >> 6;
                    const int kx0 = (idx & 63) << 2;
                    xv[k2] = *(const float4*)&inputs[(size_t)(grp * 16 + b) * S_ * IN_
                                                     + (size_t)(t + 1) * IN_ + kx0];
                }
            }

            // ---------- tag-checked gather: data + readiness in one RT ----------
            if (tid < 256) {
                unsigned int hv[8][4], cv[8][4];
                for (;;) {
                    bool ok = true;
#pragma unroll
                    for (int k = 0; k < 8; ++k) {
                        const unsigned int* bh = hph + tid * 4 + 1024 * k;
                        const unsigned int* bc = cph + tid * 4 + 1024 * k;
#pragma unroll
                        for (int e = 0; e < 4; ++e) {
                            hv[k][e] = __hip_atomic_load(bh + e, __ATOMIC_RELAXED, __HIP_MEMORY_SCOPE_AGENT);
                            cv[k][e] = __hip_atomic_load(bc + e, __ATOMIC_RELAXED, __HIP_MEMORY_SCOPE_AGENT);
                        }
                    }
#pragma unroll
                    for (int k = 0; k < 8; ++k)
#pragma unroll
                        for (int e = 0; e < 4; ++e)
                            ok = ok & ((hv[k][e] >> 16) == tag) & ((cv[k][e] >> 16) == tag);
                    if (__ballot(ok) == ~0ull) break;
                }
                // unpack to LDS fragments
#pragma unroll
                for (int k = 0; k < 8; ++k) {
                    const int ci = tid + 256 * k;       // quad index, 0..2047
                    const int s  = ci >> 6;             // slice
                    const int qd = ci & 63;             // quad within slice
                    const int b  = qd >> 2;
                    const int jj0 = (qd & 3) << 2;      // 0,4,8,12
                    const int col = s * 16 + jj0;
                    const int fi = ((col >> 3) * 16 + b) * 8 + (col & 7);
                    uint2 hp, cp;
                    hp.x = (hv[k][0] & 0xFFFFu) | (hv[k][1] << 16);
                    hp.y = (hv[k][2] & 0xFFFFu) | (hv[k][3] << 16);
                    cp.x = (cv[k][0] & 0xFFFFu) | (cv[k][1] << 16);
                    cp.y = (cv[k][2] & 0xFFFFu) | (cv[k][3] << 16);
                    *(uint2*)((f16*)A_sm + fi) = hp;
                    *(uint2*)((f16*)C_sm + fi) = cp;
                }
                // stage x(t+1) into A_sm kb 64..95
#pragma unroll
                for (int k2 = 0; k2 < 4; ++k2) {
                    const int idx = k2 * 256 + tid;
                    const int b = idx >> 6;
                    const int kx0 = (idx & 63) << 2;
                    union { f16 h[4]; uint2 u; } p;
                    p.h[0] = (f16)xv[k2].x; p.h[1] = (f16)xv[k2].y;
                    p.h[2] = (f16)xv[k2].z; p.h[3] = (f16)xv[k2].w;
                    *(uint2*)&A_sm[((64 + (kx0 >> 3)) * 16 + b) * 8 + (kx0 & 7)] = p.u;
                }
            }
            __syncthreads();
        }
    }
}

extern "C" void kernel_launch(void* const* d_in, const int* in_sizes, int n_in,
                              void* d_out, int out_size, void* d_ws, size_t ws_size,
                              hipStream_t stream) {
    const float* inputs  = (const float*)d_in[0];
    const float* tstamps = (const float*)d_in[1];
    const int*   lens    = (const int*)d_in[2];
    const float* W_all   = (const float*)d_in[3];
    const float* b_all   = (const float*)d_in[4];
    const float* U_all   = (const float*)d_in[5];
    const float* b_u     = (const float*)d_in[6];
    const float* W_d     = (const float*)d_in[7];
    const float* b_d     = (const float*)d_in[8];

    float* out0 = (float*)d_out;                    // [64,1024,512]
    float* out1 = out0 + (size_t)64 * 1024 * 512;   // last_h [64,512]
    float* out2 = out1 + (size_t)64 * 512;          // last_c [64,512]

    char* ws = (char*)d_ws;
    unsigned int* hbuf = (unsigned int*)ws;                 // 4 grp * 2 * 8192 dw = 256 KB
    unsigned int* cbuf = (unsigned int*)(ws + 262144);      // 256 KB

    // no memset needed: 0xAA poison gives tag field 0xAAAA > any real tag

    tlstm_scan<<<dim3(128), dim3(320), 0, stream>>>(
        inputs, tstamps, lens, W_all, b_all, U_all, b_u, W_d, b_d,
        out0, out1, out2, hbuf, cbuf);
}